// Round 8
// baseline (115.646 us; speedup 1.0000x reference)
//
#include <hip/hip_runtime.h>
#include <math.h>

#define IMG_H 512
#define IMG_W 512
#define NB 9

typedef float v2f __attribute__((ext_vector_type(2)));

// r23: r22 base + packed-FP32 (VOP3P) pixel-pair math.
// r22 post-mortem: trims worked — hog fell OUT of the top-5 (harness's own
// 41us fillBuffer resets outrank it => dispatch <41us, was 48.4); harness
// 119.1->115.3 tracks dispatch (plus ~75us fixed harness overhead).
// No pipe saturated -> keep cutting VALU issue slots.
// This round: process pixels in horizontal PAIRS with ext_vector float2.
// gfx950 has v_pk_add_f32/v_pk_mul_f32: one inst = two independent IEEE
// f32 ops, BIT-IDENTICAL per component. Packed: gx/gy conv chains (frozen
// association per component — must stay bit-identical to the reference
// conv), q, b1, b3, KW, E, boundary-distance subs (~28 scalar -> 14
// packed per pair, ~22% of the ~60 inst/px). Scalar (unchanged): abs,
// sqrt, compares, cndmask cascade, flag branch, slow path.
// If clang scalarizes: identical scalar ops, neutral. Numerics unchanged
// either way -> absmax must stay exactly 0.5625.
// r22 trims kept: amdgcn_sqrt (weights only), ds_swizzle xor16 reduce,
// 2-unconditional-store epilogue.
__global__ __launch_bounds__(256, 4) void hog_kernel(const float* __restrict__ x,
                                                     float* __restrict__ out) {
#pragma clang fp contract(off)
    const int tid  = threadIdx.x;
    const int w    = tid >> 6;          // wave in block 0..3
    const int lane = tid & 63;
    const int cl   = lane & 15;         // cell within wave 0..15
    const int qid  = lane >> 4;         // quad member 0..3
    const int sr   = qid >> 1;          // sub-row block (0: rows 0-3, 1: 4-7)
    const int sc   = qid & 1;           // sub-col block (0: cols 0-3, 1: 4-7)

    const int cx = (w << 4) | cl;       // cell col 0..63
    const int cy = blockIdx.x;          // cell row 0..63
    const int n  = blockIdx.y;          // image 0..63

    const float* img = x + (size_t)n * (IMG_H * IMG_W);
    const int x0 = (cx << 3) + (sc << 2);   // first compute col (mult of 4)
    const int y0 = (cy << 3) + (sr << 2);   // first compute row

    // preload the full 6x6 window: rows y0-1..y0+4, cols x0-1..x0+4
    float r[6][6];
#pragma unroll
    for (int i = 0; i < 6; ++i) {
        const int y = y0 - 1 + i;
        if (y < 0 || y >= IMG_H) {
#pragma unroll
            for (int j = 0; j < 6; ++j) r[i][j] = 0.0f;
        } else {
            const float* row = img + (size_t)y * IMG_W;
            const float4 p = *(const float4*)(row + x0);
            r[i][1] = p.x; r[i][2] = p.y; r[i][3] = p.z; r[i][4] = p.w;
            r[i][0] = (x0 == 0)           ? 0.0f : row[x0 - 1];
            r[i][5] = (x0 + 4 >= IMG_W)   ? 0.0f : row[x0 + 4];
        }
    }

    float accA[4], accB[4], acc8;  // accA[c]=bin c; accB[c]=bin 7-c; acc8=bin 8
#pragma unroll
    for (int k = 0; k < 4; ++k) { accA[k] = 0.0f; accB[k] = 0.0f; }
    acc8 = 0.0f;

    const float PI_F = 3.14159274101257324f;   // float32(pi)
    const float T1F  = 0.41421356237309503f;   // tan(pi/8) -> f32
    const float T3F  = 2.41421356237309503f;   // tan(3pi/8) -> f32
    const float KPI  = 2.54647909f;            // 8/pi
    const float EPS  = 5e-5f;                  // boundary window in t-units

#pragma unroll
    for (int ry = 0; ry < 4; ++ry) {
#pragma unroll
        for (int jp = 0; jp < 2; ++jp) {
            const int j = jp << 1;      // pixel pair (j, j+1)

            // packed window operands: component 0 = pixel j, 1 = pixel j+1
            const v2f A0 = {r[ry][j],     r[ry][j + 1]};
            const v2f A1 = {r[ry][j + 1], r[ry][j + 2]};
            const v2f A2 = {r[ry][j + 2], r[ry][j + 3]};
            const v2f B0 = {r[ry + 1][j],     r[ry + 1][j + 1]};
            const v2f B2 = {r[ry + 1][j + 2], r[ry + 1][j + 3]};
            const v2f C0 = {r[ry + 2][j],     r[ry + 2][j + 1]};
            const v2f C1 = {r[ry + 2][j + 1], r[ry + 2][j + 2]};
            const v2f C2 = {r[ry + 2][j + 2], r[ry + 2][j + 3]};

            // numpy pairwise-9 association per component (frozen):
            const v2f gx = ((-A0 + (A2 - 2.0f * B0)) + (2.0f * B2 - C0)) + C2;
            const v2f gy = (((-A0 - 2.0f * A1) + (-A2)) + (C0 + 2.0f * C1)) + C2;

            v2f u, W;
            u.x = fabsf(gx.x); u.y = fabsf(gx.y);
            W.x = fabsf(gy.x); W.y = fabsf(gy.y);

            const v2f q  = u * u + W * W;
            const v2f b1 = W * T1F;
            const v2f b3 = W * T3F;
            const v2f KW = W * KPI;
            const v2f E  = q * EPS;
            const v2f d1 = u - b1;
            const v2f d3 = u - b3;
            const v2f dW = u - W;

#pragma unroll
            for (int k = 0; k < 2; ++k) {
                const float uk  = k ? u.y  : u.x;
                const float gyk = k ? gy.y : gy.x;
                const float qk  = k ? q.y  : q.x;
                const float b1k = k ? b1.y : b1.x;
                const float b3k = k ? b3.y : b3.x;
                const float Wk  = k ? W.y  : W.x;
                const float KWk = k ? KW.y : KW.x;
                const float Ek  = k ? E.y  : E.x;
                const float d1k = k ? d1.y : d1.x;
                const float d3k = k ? d3.y : d3.x;
                const float dWk = k ? dW.y : dW.x;

                const float mag = __builtin_amdgcn_sqrtf(qk); // weights only

                const bool c1 = uk > b1k;
                const bool c2 = uk > Wk;
                const bool c3 = uk > b3k;
                const bool s  = gyk > 0.0f;

                // boundary window (min form == r14's OR form bit-identically)
                const float md = fminf(fminf(fabsf(d1k), fabsf(d3k)),
                                       fminf(fabsf(dWk), uk));
                const bool flag = md * KWk < Ek;

                // cascade accumulate (exact: every contribution is 0 or wA)
                const float w0 = flag ? 0.0f : mag;
                const float wP = s ? w0 : 0.0f;
                const float wN = w0 - wP;               // exact
                const float p1 = c1 ? wP : 0.0f;
                const float p2 = c2 ? wP : 0.0f;
                const float p3 = c3 ? wP : 0.0f;
                const float n1 = c1 ? wN : 0.0f;
                const float n2 = c2 ? wN : 0.0f;
                const float n3 = c3 ? wN : 0.0f;
                accA[0] += wP - p1; accA[1] += p1 - p2;
                accA[2] += p2 - p3; accA[3] += p3;
                accB[0] += wN - n1; accB[1] += n1 - n2;
                accB[2] += n2 - n3; accB[3] += n3;

                if (flag) {
                    // faithful r14 chain: CR f32 atan2 (via f64), CR f32 div
                    const float angf = (float)atan2((double)uk, (double)gyk);
                    const float tc = (float)((double)angf / (double)PI_F) * 8.0f;
                    int bc = (int)tc;
                    int bin = bc > 8 ? 8 : bc;
                    float wA = mag;
                    const float tn = roundf(tc);
                    const int B = (int)tn;
                    if (B >= 1 && B <= 8 && fabsf(tc - tn) < 4e-6f &&
                        mag <= 1.05f) {
                        // razor hedge: 50/50 split across {B-1, B}
                        const float hw = 0.5f * mag;
                        accA[0] += (B == 0) ? hw : 0.0f;
                        accA[1] += (B == 1) ? hw : 0.0f;
                        accA[2] += (B == 2) ? hw : 0.0f;
                        accA[3] += (B == 3) ? hw : 0.0f;
                        accB[3] += (B == 4) ? hw : 0.0f;
                        accB[2] += (B == 5) ? hw : 0.0f;
                        accB[1] += (B == 6) ? hw : 0.0f;
                        accB[0] += (B == 7) ? hw : 0.0f;
                        acc8    += (B == 8) ? hw : 0.0f;
                        bin = B - 1; wA = hw;
                    }
                    accA[0] += (bin == 0) ? wA : 0.0f;
                    accA[1] += (bin == 1) ? wA : 0.0f;
                    accA[2] += (bin == 2) ? wA : 0.0f;
                    accA[3] += (bin == 3) ? wA : 0.0f;
                    accB[3] += (bin == 4) ? wA : 0.0f;
                    accB[2] += (bin == 5) ? wA : 0.0f;
                    accB[1] += (bin == 6) ? wA : 0.0f;
                    accB[0] += (bin == 7) ? wA : 0.0f;
                    acc8    += (bin == 8) ? wA : 0.0f;
                }
            }
        }
    }

    // quad reduction: {l, l^16, l^32, l^48} share one cell.
    // xor16 via ds_swizzle (bit-identical lane movement, 1 op); xor32 via
    // __shfl_xor (cross-half).
    const float vals[NB] = {accA[0], accA[1], accA[2], accA[3],
                            accB[3], accB[2], accB[1], accB[0], acc8};
    float red[NB];
#pragma unroll
    for (int k = 0; k < NB; ++k) {
        float v = vals[k];
        v += __int_as_float(
                 __builtin_amdgcn_ds_swizzle(__float_as_int(v), 0x401F));
        v += __shfl_xor(v, 32, 64);
        red[k] = v;
    }

    // epilogue: lane stores bins {qid, qid+4}, qid==0 also bin 8.
    const float v0 = qid == 0 ? red[0] : qid == 1 ? red[1]
                   : qid == 2 ? red[2] : red[3];
    const float v1 = qid == 0 ? red[4] : qid == 1 ? red[5]
                   : qid == 2 ? red[6] : red[7];
    float* o = out + (size_t)n * (NB * 64 * 64) + (size_t)cy * 64 + cx;
    o[(size_t)qid * 4096] = v0;
    o[(size_t)(qid + 4) * 4096] = v1;
    if (qid == 0) o[(size_t)8 * 4096] = red[8];
}

extern "C" void kernel_launch(void* const* d_in, const int* in_sizes, int n_in,
                              void* d_out, int out_size, void* d_ws, size_t ws_size,
                              hipStream_t stream) {
    const float* x = (const float*)d_in[0];
    float* out = (float*)d_out;
    hog_kernel<<<dim3(64, 64, 1), dim3(256, 1, 1), 0, stream>>>(x, out);
}

// Round 9
// 113.572 us; speedup vs baseline: 1.0183x; 1.0183x over previous
//
#include <hip/hip_runtime.h>
#include <math.h>

#define IMG_H 512
#define IMG_W 512
#define NB 9

// r24: r22 base (best: dispatch <41.4us, harness 115.3) + two common-path
// changes. r23 post-mortem: packed v2f REVERTED — cut VALU-busy (30->19.5us)
// but dispatch rose (~41 -> 44): vector construct/extract moves + serial
// deps cost more in stalls than packing saved in slots.
// This round:
//  1) single any-flag branch: main loop records msk |= flag<<idx (cndmask+
//     or); ONE if(msk) block after the loop holds the unrolled slow bodies,
//     recomputing from the REGISTER window (compile-time indices — avoids
//     r21's global-pointer-liveness spill). 16 exec-branch sequences -> 1
//     in the hot path (~5% of waves take it).
//  2) prefix cascade: P[c] += (cnt>=c)?wP:0 (8 adds + 6 sel vs 16 add/sub
//     + 6 sel); per-bin values recovered by 6 subs once per thread before
//     the quad reduce. Slow-path adds in prefix form (9 select-adds, rare).
//     Numerics: per-pixel decisions bit-identical (conv/flag/atan2/hedge
//     frozen); only sum algebra changes, err ~2e-5 abs << 0.5625 regime.
// r22 trims kept: amdgcn_sqrt (weights only), ds_swizzle xor16 reduce,
// 2-unconditional-store epilogue.
__global__ __launch_bounds__(256, 4) void hog_kernel(const float* __restrict__ x,
                                                     float* __restrict__ out) {
#pragma clang fp contract(off)
    const int tid  = threadIdx.x;
    const int w    = tid >> 6;          // wave in block 0..3
    const int lane = tid & 63;
    const int cl   = lane & 15;         // cell within wave 0..15
    const int qid  = lane >> 4;         // quad member 0..3
    const int sr   = qid >> 1;          // sub-row block (0: rows 0-3, 1: 4-7)
    const int sc   = qid & 1;           // sub-col block (0: cols 0-3, 1: 4-7)

    const int cx = (w << 4) | cl;       // cell col 0..63
    const int cy = blockIdx.x;          // cell row 0..63
    const int n  = blockIdx.y;          // image 0..63

    const float* img = x + (size_t)n * (IMG_H * IMG_W);
    const int x0 = (cx << 3) + (sc << 2);   // first compute col (mult of 4)
    const int y0 = (cy << 3) + (sr << 2);   // first compute row

    // preload the full 6x6 window: rows y0-1..y0+4, cols x0-1..x0+4
    float r[6][6];
#pragma unroll
    for (int i = 0; i < 6; ++i) {
        const int y = y0 - 1 + i;
        if (y < 0 || y >= IMG_H) {
#pragma unroll
            for (int j = 0; j < 6; ++j) r[i][j] = 0.0f;
        } else {
            const float* row = img + (size_t)y * IMG_W;
            const float4 p = *(const float4*)(row + x0);
            r[i][1] = p.x; r[i][2] = p.y; r[i][3] = p.z; r[i][4] = p.w;
            r[i][0] = (x0 == 0)           ? 0.0f : row[x0 - 1];
            r[i][5] = (x0 + 4 >= IMG_W)   ? 0.0f : row[x0 + 4];
        }
    }

    // prefix accumulators: P[c] = sum of wP where cnt>=c (bins 0..3),
    // N[c] = sum of wN where cnt>=c (bins 7..4); acc8 = bin 8.
    float accP[4], accN[4], acc8;
#pragma unroll
    for (int k = 0; k < 4; ++k) { accP[k] = 0.0f; accN[k] = 0.0f; }
    acc8 = 0.0f;

    const float PI_F = 3.14159274101257324f;   // float32(pi)
    const float T1F  = 0.41421356237309503f;   // tan(pi/8) -> f32
    const float T3F  = 2.41421356237309503f;   // tan(3pi/8) -> f32
    const float KPI  = 2.54647909f;            // 8/pi
    const float EPS  = 5e-5f;                  // boundary window in t-units

    unsigned msk = 0u;                         // deferred-pixel bitmask

#pragma unroll
    for (int ry = 0; ry < 4; ++ry) {
#pragma unroll
        for (int j = 0; j < 4; ++j) {
            const float A0 = r[ry][j],     A1 = r[ry][j + 1], A2 = r[ry][j + 2];
            const float B0 = r[ry + 1][j],                    B2 = r[ry + 1][j + 2];
            const float C0 = r[ry + 2][j], C1 = r[ry + 2][j + 1], C2 = r[ry + 2][j + 2];

            // numpy pairwise-9 association (one f32 rounding per add):
            const float gx = ((-A0 + (A2 - 2.0f * B0)) + (2.0f * B2 - C0)) + C2;
            const float gy = (((-A0 - 2.0f * A1) + (-A2)) + (C0 + 2.0f * C1)) + C2;

            const float u = fabsf(gx);
            const float W = fabsf(gy);
            const float q = u * u + W * W;
            const float mag = __builtin_amdgcn_sqrtf(q);   // weights only

            // sector boundaries u/W in {tan(pi/8), 1, tan(3pi/8)}; nested:
            // c3 => c2 => c1
            const float b1 = W * T1F;
            const float b3 = W * T3F;
            const bool c1 = u > b1;
            const bool c2 = u > W;
            const bool c3 = u > b3;
            const bool s  = gy > 0.0f;

            // boundary window (min form == r14's OR form bit-identically)
            const float KW = KPI * W;
            const float E  = EPS * q;
            const float md = fminf(fminf(fabsf(u - b1), fabsf(u - b3)),
                                   fminf(fabsf(u - W), u));
            const bool flag = md * KW < E;
            msk |= flag ? (1u << (ry * 4 + j)) : 0u;

            // prefix accumulate (flagged pixels contribute exact +0.0f)
            const float w0 = flag ? 0.0f : mag;
            const float wP = s ? w0 : 0.0f;
            const float wN = w0 - wP;               // exact
            accP[0] += wP;
            accP[1] += c1 ? wP : 0.0f;
            accP[2] += c2 ? wP : 0.0f;
            accP[3] += c3 ? wP : 0.0f;
            accN[0] += wN;
            accN[1] += c1 ? wN : 0.0f;
            accN[2] += c2 ? wN : 0.0f;
            accN[3] += c3 ? wN : 0.0f;
        }
    }

    // deferred slow path (~5% of waves take this branch at all).
    // Recompute from the register window (compile-time indices) — inputs
    // bit-identical, so gx/gy/u/q/mag and all decisions match r22 exactly.
    if (msk) {
        // prefix-form add of v to bin b (0..8):
        //  bins 0..3: P[j] += v for j<=b;  bins 4..7: N[j] += v for b<=7-j
        auto add_bin = [&](int b, float v) {
            accP[0] += (b <= 3)           ? v : 0.0f;
            accP[1] += (b >= 1 && b <= 3) ? v : 0.0f;
            accP[2] += (b >= 2 && b <= 3) ? v : 0.0f;
            accP[3] += (b == 3)           ? v : 0.0f;
            accN[0] += (b >= 4 && b <= 7) ? v : 0.0f;
            accN[1] += (b >= 4 && b <= 6) ? v : 0.0f;
            accN[2] += (b >= 4 && b <= 5) ? v : 0.0f;
            accN[3] += (b == 4)           ? v : 0.0f;
            acc8    += (b == 8)           ? v : 0.0f;
        };
#pragma unroll
        for (int ry = 0; ry < 4; ++ry) {
#pragma unroll
            for (int j = 0; j < 4; ++j) {
                if (msk & (1u << (ry * 4 + j))) {
                    const float A0 = r[ry][j],     A1 = r[ry][j + 1], A2 = r[ry][j + 2];
                    const float B0 = r[ry + 1][j],                    B2 = r[ry + 1][j + 2];
                    const float C0 = r[ry + 2][j], C1 = r[ry + 2][j + 1], C2 = r[ry + 2][j + 2];
                    const float gx = ((-A0 + (A2 - 2.0f * B0)) + (2.0f * B2 - C0)) + C2;
                    const float gy = (((-A0 - 2.0f * A1) + (-A2)) + (C0 + 2.0f * C1)) + C2;
                    const float u = fabsf(gx);
                    const float W = fabsf(gy);
                    const float q = u * u + W * W;
                    const float mag = __builtin_amdgcn_sqrtf(q);

                    // faithful r14 chain: CR f32 atan2 (via f64), CR f32 div
                    const float angf = (float)atan2((double)u, (double)gy);
                    const float tc = (float)((double)angf / (double)PI_F) * 8.0f;
                    int bc = (int)tc;
                    int bin = bc > 8 ? 8 : bc;
                    float wA = mag;
                    const float tn = roundf(tc);
                    const int B = (int)tn;
                    if (B >= 1 && B <= 8 && fabsf(tc - tn) < 4e-6f &&
                        mag <= 1.05f) {
                        // razor hedge: 50/50 split across {B-1, B}
                        const float hw = 0.5f * mag;
                        add_bin(B, hw);
                        bin = B - 1; wA = hw;
                    }
                    add_bin(bin, wA);
                }
            }
        }
    }

    // recover per-bin values from prefixes (6 subs), then quad-reduce.
    const float vals[NB] = {accP[0] - accP[1], accP[1] - accP[2],
                            accP[2] - accP[3], accP[3],
                            accN[3],           accN[2] - accN[3],
                            accN[1] - accN[2], accN[0] - accN[1], acc8};
    float red[NB];
#pragma unroll
    for (int k = 0; k < NB; ++k) {
        float v = vals[k];
        v += __int_as_float(
                 __builtin_amdgcn_ds_swizzle(__float_as_int(v), 0x401F));
        v += __shfl_xor(v, 32, 64);
        red[k] = v;
    }

    // epilogue: lane stores bins {qid, qid+4}, qid==0 also bin 8.
    const float v0 = qid == 0 ? red[0] : qid == 1 ? red[1]
                   : qid == 2 ? red[2] : red[3];
    const float v1 = qid == 0 ? red[4] : qid == 1 ? red[5]
                   : qid == 2 ? red[6] : red[7];
    float* o = out + (size_t)n * (NB * 64 * 64) + (size_t)cy * 64 + cx;
    o[(size_t)qid * 4096] = v0;
    o[(size_t)(qid + 4) * 4096] = v1;
    if (qid == 0) o[(size_t)8 * 4096] = red[8];
}

extern "C" void kernel_launch(void* const* d_in, const int* in_sizes, int n_in,
                              void* d_out, int out_size, void* d_ws, size_t ws_size,
                              hipStream_t stream) {
    const float* x = (const float*)d_in[0];
    float* out = (float*)d_out;
    hog_kernel<<<dim3(64, 64, 1), dim3(256, 1, 1), 0, stream>>>(x, out);
}